// Round 3
// baseline (322.303 us; speedup 1.0000x reference)
//
#include <hip/hip_runtime.h>

// QuantizerEncoder: code[n,h,w,m] = argmax_k < wq[m] @ q_raw[n,h,w,m], wk[m] @ cb[m,k] >
// n=16, d=512, h=64, w=64, m=4, kcodes=256, dm=128
//
// Round 8: LDS overhaul in argmax_mfma (total 284us; argmax ~54us inferred, rest is
// harness fill overhead ~230us visible as 77us fillBufferAligned dispatches).
//  - RSH 132 -> 136 halfs (272B rows): 16B-aligned -> B-frags load as ONE ds_read_b128
//    (was 2x ds_read_b64 + shufflevector, 4-way bank conflicts at 66-dword stride).
//    Bank check: dword base = 4*(col+quad) mod 32 -> 8 disjoint 4-dword windows x 8
//    lanes = 8-cycle floor, conflict-free.
//  - Staging writes transposed in registers: thread packs 8 d-planes of one pixel into
//    f16x8 -> 4x ds_write_b128 per row (was 16x 4B writes, ~8-way conflicts).
//    Bank base = 16*(t15&1)+4*g -> disjoint windows, conflict-free.
//  - Rounding stays RTN ((_Float16) casts): EPS=0.045 rescue margin assumes RTN error.
//  - __launch_bounds__(256,4): LDS 37,888B -> exactly 4 blocks/CU, grid 1024 = 4x256.

#define MM   4
#define KC   256
#define DM   128
#define HW   4096   // h*w
#define WW_  64
#define EPS  0.045f
#define WL_CAP 65536
#define RSH  136    // LDS row stride in halfs (272B, 16B-aligned, conflict-free b128)

typedef _Float16 f16x8 __attribute__((ext_vector_type(8)));
typedef _Float16 f16x4 __attribute__((ext_vector_type(4)));
typedef _Float16 f16x2 __attribute__((ext_vector_type(2)));
typedef float    f32x4 __attribute__((ext_vector_type(4)));

// ---- Kernel 1: A[m][e][d] = sum_c wk[m][c][e] * wq[m][c][d]  (fp64) ----
__global__ __launch_bounds__(128) void a_kernel(const float* __restrict__ wk,
                                                const float* __restrict__ wq,
                                                double* __restrict__ A) {
    int me = blockIdx.x;           // m*128 + e
    int d  = threadIdx.x;
    int m  = me >> 7;
    int e  = me & 127;
    const float* wkm = wk + (size_t)m * DM * DM + e;       // wk[m][c][e], stride DM
    const float* wqm = wq + (size_t)m * DM * DM + d;       // wq[m][c][d], stride DM
    double s0 = 0.0, s1 = 0.0, s2 = 0.0, s3 = 0.0;
#pragma unroll 8
    for (int c = 0; c < DM; c += 4) {
        s0 = fma((double)wkm[(size_t)(c+0) * DM], (double)wqm[(size_t)(c+0) * DM], s0);
        s1 = fma((double)wkm[(size_t)(c+1) * DM], (double)wqm[(size_t)(c+1) * DM], s1);
        s2 = fma((double)wkm[(size_t)(c+2) * DM], (double)wqm[(size_t)(c+2) * DM], s2);
        s3 = fma((double)wkm[(size_t)(c+3) * DM], (double)wqm[(size_t)(c+3) * DM], s3);
    }
    A[(size_t)me * DM + d] = (s0 + s1) + (s2 + s3);
}

// ---- Kernel 2: keff[m][k][d] = sum_e cb[m][k][e]*A[m][e][d]; store fp16 + fp64-transposed ----
__global__ __launch_bounds__(128) void keff_kernel(const float* __restrict__ cb,
                                                   const double* __restrict__ A,
                                                   double* __restrict__ keffdT,
                                                   _Float16* __restrict__ keff16) {
    int mk = blockIdx.x;           // m*256 + k
    int d  = threadIdx.x;
    int m  = mk >> 8;
    int k  = mk & 255;
    const float*  cbr = cb + (size_t)mk * DM;              // cb[m][k][*]
    const double* Am  = A + (size_t)m * DM * DM + d;       // A[m][e][d], stride DM
    double s0 = 0.0, s1 = 0.0, s2 = 0.0, s3 = 0.0;
#pragma unroll 8
    for (int e = 0; e < DM; e += 4) {
        s0 = fma((double)cbr[e+0], Am[(size_t)(e+0) * DM], s0);
        s1 = fma((double)cbr[e+1], Am[(size_t)(e+1) * DM], s1);
        s2 = fma((double)cbr[e+2], Am[(size_t)(e+2) * DM], s2);
        s3 = fma((double)cbr[e+3], Am[(size_t)(e+3) * DM], s3);
    }
    double s = (s0 + s1) + (s2 + s3);
    keffdT[((size_t)m * DM + d) * KC + k] = s;             // transposed: rescue reads coalesced
    keff16[(size_t)mk * DM + d] = (_Float16)s;
}

// ---- Kernel 3: MFMA argmax, 4 rows per block, 1024 blocks ----
__global__ __launch_bounds__(256, 4) void argmax_mfma(const float* __restrict__ latent,
                                                      const _Float16* __restrict__ keff16,
                                                      int* __restrict__ out,
                                                      int* __restrict__ wl_cnt,
                                                      int* __restrict__ wl) {
    __shared__ _Float16 lq[2][64 * RSH];   // 2 x 17,408 B q tiles
    __shared__ float pbv[64][4];
    __shared__ float psv[64][4];
    __shared__ int   pbi[64][4];

    int blk  = blockIdx.x;          // 0..1023 = n(16) x m(4) x hg(16)
    int n    = blk >> 6;
    int m    = (blk >> 4) & 3;
    int hg   = blk & 15;
    int tid  = threadIdx.x;
    int wave = tid >> 6;
    int lane = tid & 63;
    int col  = lane & 15;
    int quad = lane >> 4;
    int w4   = (tid & 15) * 4;      // staging: pixel base (float4 along w)
    int db   = (tid >> 4) * 8;      // staging: d-plane base (16 groups x 8 = 128)

    // ---- A-frags: this wave's 64 codes, resident in 64 VGPRs for the whole block ----
    // A[mrow=code (lane&15 within tile)][k = quad*8+j]
    f16x8 Af[4][4];
    {
        const _Float16* kbase = keff16 + ((size_t)m * KC + wave * 64) * DM;
#pragma unroll
        for (int t = 0; t < 4; ++t)
#pragma unroll
            for (int s = 0; s < 4; ++s)
                Af[t][s] = *(const f16x8*)(kbase + (size_t)(t * 16 + col) * DM + s * 32 + quad * 8);
    }

    const float* lp0 = latent + ((size_t)(n * 512 + m * DM)) * HW + (size_t)(hg * 4) * WW_;

    // ---- stage row 0: load 8 planes x 4 pixels, register-transpose, 4x ds_write_b128 ----
    {
        f32x4 pf[8];
#pragma unroll
        for (int pp = 0; pp < 8; ++pp)
            pf[pp] = *(const f32x4*)(lp0 + (size_t)(db + pp) * HW + w4);
#pragma unroll
        for (int j = 0; j < 4; ++j) {
            f16x8 v;
#pragma unroll
            for (int pp = 0; pp < 8; ++pp) v[pp] = (_Float16)pf[pp][j];
            *(f16x8*)&lq[0][(size_t)(w4 + j) * RSH + db] = v;
        }
    }
    __syncthreads();

    for (int r = 0; r < 4; ++r) {
        int cur = r & 1;

        // ---- prefetch next row: raw float4 regs, convert LATER (after epilogue) ----
        f32x4 pf[8];
        if (r < 3) {
            const float* lp = lp0 + (size_t)(r + 1) * WW_;
#pragma unroll
            for (int pp = 0; pp < 8; ++pp)
                pf[pp] = *(const f32x4*)(lp + (size_t)(db + pp) * HW + w4);
        }

        // ---- compute + epilogue fused per pixel-tile p (acc live regs: 16) ----
#pragma unroll
        for (int p = 0; p < 4; ++p) {
            f16x8 Bf[4];
#pragma unroll
            for (int s = 0; s < 4; ++s)
                Bf[s] = *(const f16x8*)&lq[cur][(size_t)(p * 16 + col) * RSH + s * 32 + quad * 8];
            f32x4 acc[4];
#pragma unroll
            for (int t = 0; t < 4; ++t) {
                f32x4 c = (f32x4){0.f, 0.f, 0.f, 0.f};
                c = __builtin_amdgcn_mfma_f32_16x16x32_f16(Af[t][0], Bf[0], c, 0, 0, 0);
                c = __builtin_amdgcn_mfma_f32_16x16x32_f16(Af[t][1], Bf[1], c, 0, 0, 0);
                c = __builtin_amdgcn_mfma_f32_16x16x32_f16(Af[t][2], Bf[2], c, 0, 0, 0);
                c = __builtin_amdgcn_mfma_f32_16x16x32_f16(Af[t][3], Bf[3], c, 0, 0, 0);
                acc[t] = c;
            }
            // C col=pixel-in-tile, row=quad*4+reg=code-in-tile
            float bv = acc[0][0];
            int   bi = wave * 64 + quad * 4;
            float sv = -3.0e38f;
#pragma unroll
            for (int t = 0; t < 4; ++t)
#pragma unroll
                for (int g = 0; g < 4; ++g) {
                    if (t == 0 && g == 0) continue;
                    float v   = acc[t][g];
                    int   idx = wave * 64 + t * 16 + quad * 4 + g;   // ascending scan
                    if (v > bv)      { sv = bv; bv = v; bi = idx; }
                    else if (v > sv) sv = v;
                }
            // merge across the 4 quads holding this pixel
#pragma unroll
            for (int off = 16; off < 64; off <<= 1) {
                float ov = __shfl_xor(bv, off);
                int   oi = __shfl_xor(bi, off);
                float os = __shfl_xor(sv, off);
                bool  take  = (ov > bv) || (ov == bv && oi < bi);
                float loser = take ? bv : ov;
                sv = fmaxf(fmaxf(sv, os), loser);
                if (take) { bv = ov; bi = oi; }
            }
            if (quad == 0) {
                int P = p * 16 + col;
                pbv[P][wave] = bv; psv[P][wave] = sv; pbi[P][wave] = bi;
            }
        }
        __syncthreads();

        // ---- cross-wave merge + output (64 threads) ----
        if (tid < 64) {
            int   P  = tid;
            float bv = pbv[P][0]; float sv = psv[P][0]; int bi = pbi[P][0];
#pragma unroll
            for (int wv = 1; wv < 4; ++wv) {
                float ov = pbv[P][wv]; float os = psv[P][wv]; int oi = pbi[P][wv];
                bool  take  = (ov > bv) || (ov == bv && oi < bi);
                float loser = take ? bv : ov;
                sv = fmaxf(fmaxf(sv, os), loser);
                if (take) { bv = ov; bi = oi; }
            }
            int h   = hg * 4 + r;
            int pix = (((n * 64 + h) * 64) + P) * MM + m;
            out[pix] = bi;
            if (bv - sv < EPS) {
                int slot = atomicAdd(wl_cnt, 1);
                if (slot < WL_CAP) wl[slot] = pix;
            }
        }

        // ---- deferred staging: register-transpose prefetched planes, 4x ds_write_b128 ----
        if (r < 3) {
#pragma unroll
            for (int j = 0; j < 4; ++j) {
                f16x8 v;
#pragma unroll
                for (int pp = 0; pp < 8; ++pp) v[pp] = (_Float16)pf[pp][j];
                *(f16x8*)&lq[cur ^ 1][(size_t)(w4 + j) * RSH + db] = v;
            }
        }
        __syncthreads();
    }
}

// ---- Kernel 4: fp64 canonical rescue (coalesced keffdT reads) ----
__global__ __launch_bounds__(256) void rescue_kernel(const float* __restrict__ latent,
                                                     const double* __restrict__ keffdT,
                                                     const int* __restrict__ wl_cnt,
                                                     const int* __restrict__ wl,
                                                     int* __restrict__ out) {
    __shared__ double sq[DM];
    __shared__ double svals[256];
    __shared__ int    sidx[256];
    int cnt = *wl_cnt;
    if (cnt > WL_CAP) cnt = WL_CAP;
    int t = threadIdx.x;
    for (int i = blockIdx.x; i < cnt; i += gridDim.x) {
        int pix = wl[i];
        int m   = pix & 3;
        int rem = pix >> 2;          // (n*64+h)*64 + w
        int w   = rem & 63;
        int bh  = rem >> 6;          // n*64+h
        int n   = bh >> 6;
        int h   = bh & 63;
        const float* lp = latent + ((size_t)(n * 512 + m * DM)) * HW + h * WW_ + w;
        if (t < DM) sq[t] = (double)lp[(size_t)t * HW];
        __syncthreads();
        const double* kr = keffdT + (size_t)m * DM * KC + t;   // [d][k=t]: lanes coalesced
        double s0 = 0.0, s1 = 0.0, s2 = 0.0, s3 = 0.0;
#pragma unroll 8
        for (int d = 0; d < DM; d += 4) {
            s0 = fma(sq[d+0], kr[(size_t)(d+0) * KC], s0);
            s1 = fma(sq[d+1], kr[(size_t)(d+1) * KC], s1);
            s2 = fma(sq[d+2], kr[(size_t)(d+2) * KC], s2);
            s3 = fma(sq[d+3], kr[(size_t)(d+3) * KC], s3);
        }
        svals[t] = (s0 + s1) + (s2 + s3);
        sidx[t]  = t;
        __syncthreads();
        for (int stp = 128; stp > 0; stp >>= 1) {
            if (t < stp) {
                double vo = svals[t + stp], vm = svals[t];
                int io = sidx[t + stp], im = sidx[t];
                if (vo > vm || (vo == vm && io < im)) { svals[t] = vo; sidx[t] = io; }
            }
            __syncthreads();
        }
        if (t == 0) out[pix] = sidx[0];
        __syncthreads();
    }
}

extern "C" void kernel_launch(void* const* d_in, const int* in_sizes, int n_in,
                              void* d_out, int out_size, void* d_ws, size_t ws_size,
                              hipStream_t stream) {
    const float* latent = (const float*)d_in[0];   // [16,512,64,64]
    const float* cb     = (const float*)d_in[1];   // [4,256,128]
    const float* wq     = (const float*)d_in[2];   // [4,128,128]
    const float* wk     = (const float*)d_in[3];   // [4,128,128]
    int* out = (int*)d_out;                        // 262144 code indices (int32)

    // workspace layout (~2.1 MB)
    char* ws = (char*)d_ws;
    double*   A      = (double*)ws;     ws += (size_t)MM * DM * DM * sizeof(double);    // 512 KB
    double*   keffdT = (double*)ws;     ws += (size_t)MM * DM * KC * sizeof(double);    // 1 MB
    _Float16* keff16 = (_Float16*)ws;   ws += (size_t)MM * KC * DM * sizeof(_Float16);  // 256 KB
    int*      wl_cnt = (int*)ws;        ws += 256;
    int*      wl     = (int*)ws;        // WL_CAP * 4 = 256 KB

    hipMemsetAsync(wl_cnt, 0, sizeof(int), stream);
    a_kernel<<<MM * DM, 128, 0, stream>>>(wk, wq, A);
    keff_kernel<<<MM * KC, 128, 0, stream>>>(cb, A, keffdT, keff16);
    argmax_mfma<<<1024, 256, 0, stream>>>(latent, keff16, out, wl_cnt, wl);
    rescue_kernel<<<1024, 256, 0, stream>>>(latent, keffdT, wl_cnt, wl, out);
}

// Round 4
// 283.102 us; speedup vs baseline: 1.1385x; 1.1385x over previous
//
#include <hip/hip_runtime.h>

// QuantizerEncoder: code[n,h,w,m] = argmax_k < wq[m] @ q_raw[n,h,w,m], wk[m] @ cb[m,k] >
// n=16, d=512, h=64, w=64, m=4, kcodes=256, dm=128
//
// Round 9: fix round-8 regression. (256,4) capped unified VGPR/AGPR at 128/wave ->
// compiler spilled (VGPR_Count 64, WRITE_SIZE 1.3->49.5MB scratch traffic, argmax
// 54->118us despite occupancy 20->43%). Revert to __launch_bounds__(256,3) (cap ~170,
// live set ~155, no spill). KEEP the round-8 LDS overhaul (proven cheaper per-op):
//  - RSH 136 halfs (272B rows, 16B-aligned): B-frags = ONE ds_read_b128 each,
//    8 disjoint 4-dword bank windows x 8 lanes = b128 floor (the 2.99M "conflicts"
//    normalize to ~8.7cyc/b128 op = the unavoidable wide-access serialization).
//  - Staging register-transposed: 4x ds_write_b128 per row (was 16x 4B writes).
//  - RTN rounding kept ((_Float16) casts): EPS=0.045 rescue margin assumes RTN.

#define MM   4
#define KC   256
#define DM   128
#define HW   4096   // h*w
#define WW_  64
#define EPS  0.045f
#define WL_CAP 65536
#define RSH  136    // LDS row stride in halfs (272B, 16B-aligned, conflict-free b128)

typedef _Float16 f16x8 __attribute__((ext_vector_type(8)));
typedef _Float16 f16x4 __attribute__((ext_vector_type(4)));
typedef _Float16 f16x2 __attribute__((ext_vector_type(2)));
typedef float    f32x4 __attribute__((ext_vector_type(4)));

// ---- Kernel 1: A[m][e][d] = sum_c wk[m][c][e] * wq[m][c][d]  (fp64) ----
__global__ __launch_bounds__(128) void a_kernel(const float* __restrict__ wk,
                                                const float* __restrict__ wq,
                                                double* __restrict__ A) {
    int me = blockIdx.x;           // m*128 + e
    int d  = threadIdx.x;
    int m  = me >> 7;
    int e  = me & 127;
    const float* wkm = wk + (size_t)m * DM * DM + e;       // wk[m][c][e], stride DM
    const float* wqm = wq + (size_t)m * DM * DM + d;       // wq[m][c][d], stride DM
    double s0 = 0.0, s1 = 0.0, s2 = 0.0, s3 = 0.0;
#pragma unroll 8
    for (int c = 0; c < DM; c += 4) {
        s0 = fma((double)wkm[(size_t)(c+0) * DM], (double)wqm[(size_t)(c+0) * DM], s0);
        s1 = fma((double)wkm[(size_t)(c+1) * DM], (double)wqm[(size_t)(c+1) * DM], s1);
        s2 = fma((double)wkm[(size_t)(c+2) * DM], (double)wqm[(size_t)(c+2) * DM], s2);
        s3 = fma((double)wkm[(size_t)(c+3) * DM], (double)wqm[(size_t)(c+3) * DM], s3);
    }
    A[(size_t)me * DM + d] = (s0 + s1) + (s2 + s3);
}

// ---- Kernel 2: keff[m][k][d] = sum_e cb[m][k][e]*A[m][e][d]; store fp16 + fp64-transposed ----
__global__ __launch_bounds__(128) void keff_kernel(const float* __restrict__ cb,
                                                   const double* __restrict__ A,
                                                   double* __restrict__ keffdT,
                                                   _Float16* __restrict__ keff16) {
    int mk = blockIdx.x;           // m*256 + k
    int d  = threadIdx.x;
    int m  = mk >> 8;
    int k  = mk & 255;
    const float*  cbr = cb + (size_t)mk * DM;              // cb[m][k][*]
    const double* Am  = A + (size_t)m * DM * DM + d;       // A[m][e][d], stride DM
    double s0 = 0.0, s1 = 0.0, s2 = 0.0, s3 = 0.0;
#pragma unroll 8
    for (int e = 0; e < DM; e += 4) {
        s0 = fma((double)cbr[e+0], Am[(size_t)(e+0) * DM], s0);
        s1 = fma((double)cbr[e+1], Am[(size_t)(e+1) * DM], s1);
        s2 = fma((double)cbr[e+2], Am[(size_t)(e+2) * DM], s2);
        s3 = fma((double)cbr[e+3], Am[(size_t)(e+3) * DM], s3);
    }
    double s = (s0 + s1) + (s2 + s3);
    keffdT[((size_t)m * DM + d) * KC + k] = s;             // transposed: rescue reads coalesced
    keff16[(size_t)mk * DM + d] = (_Float16)s;
}

// ---- Kernel 3: MFMA argmax, 4 rows per block, 1024 blocks ----
__global__ __launch_bounds__(256, 3) void argmax_mfma(const float* __restrict__ latent,
                                                      const _Float16* __restrict__ keff16,
                                                      int* __restrict__ out,
                                                      int* __restrict__ wl_cnt,
                                                      int* __restrict__ wl) {
    __shared__ _Float16 lq[2][64 * RSH];   // 2 x 17,408 B q tiles
    __shared__ float pbv[64][4];
    __shared__ float psv[64][4];
    __shared__ int   pbi[64][4];

    int blk  = blockIdx.x;          // 0..1023 = n(16) x m(4) x hg(16)
    int n    = blk >> 6;
    int m    = (blk >> 4) & 3;
    int hg   = blk & 15;
    int tid  = threadIdx.x;
    int wave = tid >> 6;
    int lane = tid & 63;
    int col  = lane & 15;
    int quad = lane >> 4;
    int w4   = (tid & 15) * 4;      // staging: pixel base (float4 along w)
    int db   = (tid >> 4) * 8;      // staging: d-plane base (16 groups x 8 = 128)

    // ---- A-frags: this wave's 64 codes, resident in 64 VGPRs for the whole block ----
    // A[mrow=code (lane&15 within tile)][k = quad*8+j]
    f16x8 Af[4][4];
    {
        const _Float16* kbase = keff16 + ((size_t)m * KC + wave * 64) * DM;
#pragma unroll
        for (int t = 0; t < 4; ++t)
#pragma unroll
            for (int s = 0; s < 4; ++s)
                Af[t][s] = *(const f16x8*)(kbase + (size_t)(t * 16 + col) * DM + s * 32 + quad * 8);
    }

    const float* lp0 = latent + ((size_t)(n * 512 + m * DM)) * HW + (size_t)(hg * 4) * WW_;

    // ---- stage row 0: load 8 planes x 4 pixels, register-transpose, 4x ds_write_b128 ----
    {
        f32x4 pf[8];
#pragma unroll
        for (int pp = 0; pp < 8; ++pp)
            pf[pp] = *(const f32x4*)(lp0 + (size_t)(db + pp) * HW + w4);
#pragma unroll
        for (int j = 0; j < 4; ++j) {
            f16x8 v;
#pragma unroll
            for (int pp = 0; pp < 8; ++pp) v[pp] = (_Float16)pf[pp][j];
            *(f16x8*)&lq[0][(size_t)(w4 + j) * RSH + db] = v;
        }
    }
    __syncthreads();

    for (int r = 0; r < 4; ++r) {
        int cur = r & 1;

        // ---- prefetch next row: raw float4 regs, convert LATER (after epilogue) ----
        f32x4 pf[8];
        if (r < 3) {
            const float* lp = lp0 + (size_t)(r + 1) * WW_;
#pragma unroll
            for (int pp = 0; pp < 8; ++pp)
                pf[pp] = *(const f32x4*)(lp + (size_t)(db + pp) * HW + w4);
        }

        // ---- compute + epilogue fused per pixel-tile p (acc live regs: 16) ----
#pragma unroll
        for (int p = 0; p < 4; ++p) {
            f16x8 Bf[4];
#pragma unroll
            for (int s = 0; s < 4; ++s)
                Bf[s] = *(const f16x8*)&lq[cur][(size_t)(p * 16 + col) * RSH + s * 32 + quad * 8];
            f32x4 acc[4];
#pragma unroll
            for (int t = 0; t < 4; ++t) {
                f32x4 c = (f32x4){0.f, 0.f, 0.f, 0.f};
                c = __builtin_amdgcn_mfma_f32_16x16x32_f16(Af[t][0], Bf[0], c, 0, 0, 0);
                c = __builtin_amdgcn_mfma_f32_16x16x32_f16(Af[t][1], Bf[1], c, 0, 0, 0);
                c = __builtin_amdgcn_mfma_f32_16x16x32_f16(Af[t][2], Bf[2], c, 0, 0, 0);
                c = __builtin_amdgcn_mfma_f32_16x16x32_f16(Af[t][3], Bf[3], c, 0, 0, 0);
                acc[t] = c;
            }
            // C col=pixel-in-tile, row=quad*4+reg=code-in-tile
            float bv = acc[0][0];
            int   bi = wave * 64 + quad * 4;
            float sv = -3.0e38f;
#pragma unroll
            for (int t = 0; t < 4; ++t)
#pragma unroll
                for (int g = 0; g < 4; ++g) {
                    if (t == 0 && g == 0) continue;
                    float v   = acc[t][g];
                    int   idx = wave * 64 + t * 16 + quad * 4 + g;   // ascending scan
                    if (v > bv)      { sv = bv; bv = v; bi = idx; }
                    else if (v > sv) sv = v;
                }
            // merge across the 4 quads holding this pixel
#pragma unroll
            for (int off = 16; off < 64; off <<= 1) {
                float ov = __shfl_xor(bv, off);
                int   oi = __shfl_xor(bi, off);
                float os = __shfl_xor(sv, off);
                bool  take  = (ov > bv) || (ov == bv && oi < bi);
                float loser = take ? bv : ov;
                sv = fmaxf(fmaxf(sv, os), loser);
                if (take) { bv = ov; bi = oi; }
            }
            if (quad == 0) {
                int P = p * 16 + col;
                pbv[P][wave] = bv; psv[P][wave] = sv; pbi[P][wave] = bi;
            }
        }
        __syncthreads();

        // ---- cross-wave merge + output (64 threads) ----
        if (tid < 64) {
            int   P  = tid;
            float bv = pbv[P][0]; float sv = psv[P][0]; int bi = pbi[P][0];
#pragma unroll
            for (int wv = 1; wv < 4; ++wv) {
                float ov = pbv[P][wv]; float os = psv[P][wv]; int oi = pbi[P][wv];
                bool  take  = (ov > bv) || (ov == bv && oi < bi);
                float loser = take ? bv : ov;
                sv = fmaxf(fmaxf(sv, os), loser);
                if (take) { bv = ov; bi = oi; }
            }
            int h   = hg * 4 + r;
            int pix = (((n * 64 + h) * 64) + P) * MM + m;
            out[pix] = bi;
            if (bv - sv < EPS) {
                int slot = atomicAdd(wl_cnt, 1);
                if (slot < WL_CAP) wl[slot] = pix;
            }
        }

        // ---- deferred staging: register-transpose prefetched planes, 4x ds_write_b128 ----
        if (r < 3) {
#pragma unroll
            for (int j = 0; j < 4; ++j) {
                f16x8 v;
#pragma unroll
                for (int pp = 0; pp < 8; ++pp) v[pp] = (_Float16)pf[pp][j];
                *(f16x8*)&lq[cur ^ 1][(size_t)(w4 + j) * RSH + db] = v;
            }
        }
        __syncthreads();
    }
}

// ---- Kernel 4: fp64 canonical rescue (coalesced keffdT reads) ----
__global__ __launch_bounds__(256) void rescue_kernel(const float* __restrict__ latent,
                                                     const double* __restrict__ keffdT,
                                                     const int* __restrict__ wl_cnt,
                                                     const int* __restrict__ wl,
                                                     int* __restrict__ out) {
    __shared__ double sq[DM];
    __shared__ double svals[256];
    __shared__ int    sidx[256];
    int cnt = *wl_cnt;
    if (cnt > WL_CAP) cnt = WL_CAP;
    int t = threadIdx.x;
    for (int i = blockIdx.x; i < cnt; i += gridDim.x) {
        int pix = wl[i];
        int m   = pix & 3;
        int rem = pix >> 2;          // (n*64+h)*64 + w
        int w   = rem & 63;
        int bh  = rem >> 6;          // n*64+h
        int n   = bh >> 6;
        int h   = bh & 63;
        const float* lp = latent + ((size_t)(n * 512 + m * DM)) * HW + h * WW_ + w;
        if (t < DM) sq[t] = (double)lp[(size_t)t * HW];
        __syncthreads();
        const double* kr = keffdT + (size_t)m * DM * KC + t;   // [d][k=t]: lanes coalesced
        double s0 = 0.0, s1 = 0.0, s2 = 0.0, s3 = 0.0;
#pragma unroll 8
        for (int d = 0; d < DM; d += 4) {
            s0 = fma(sq[d+0], kr[(size_t)(d+0) * KC], s0);
            s1 = fma(sq[d+1], kr[(size_t)(d+1) * KC], s1);
            s2 = fma(sq[d+2], kr[(size_t)(d+2) * KC], s2);
            s3 = fma(sq[d+3], kr[(size_t)(d+3) * KC], s3);
        }
        svals[t] = (s0 + s1) + (s2 + s3);
        sidx[t]  = t;
        __syncthreads();
        for (int stp = 128; stp > 0; stp >>= 1) {
            if (t < stp) {
                double vo = svals[t + stp], vm = svals[t];
                int io = sidx[t + stp], im = sidx[t];
                if (vo > vm || (vo == vm && io < im)) { svals[t] = vo; sidx[t] = io; }
            }
            __syncthreads();
        }
        if (t == 0) out[pix] = sidx[0];
        __syncthreads();
    }
}

extern "C" void kernel_launch(void* const* d_in, const int* in_sizes, int n_in,
                              void* d_out, int out_size, void* d_ws, size_t ws_size,
                              hipStream_t stream) {
    const float* latent = (const float*)d_in[0];   // [16,512,64,64]
    const float* cb     = (const float*)d_in[1];   // [4,256,128]
    const float* wq     = (const float*)d_in[2];   // [4,128,128]
    const float* wk     = (const float*)d_in[3];   // [4,128,128]
    int* out = (int*)d_out;                        // 262144 code indices (int32)

    // workspace layout (~2.1 MB)
    char* ws = (char*)d_ws;
    double*   A      = (double*)ws;     ws += (size_t)MM * DM * DM * sizeof(double);    // 512 KB
    double*   keffdT = (double*)ws;     ws += (size_t)MM * DM * KC * sizeof(double);    // 1 MB
    _Float16* keff16 = (_Float16*)ws;   ws += (size_t)MM * KC * DM * sizeof(_Float16);  // 256 KB
    int*      wl_cnt = (int*)ws;        ws += 256;
    int*      wl     = (int*)ws;        // WL_CAP * 4 = 256 KB

    hipMemsetAsync(wl_cnt, 0, sizeof(int), stream);
    a_kernel<<<MM * DM, 128, 0, stream>>>(wk, wq, A);
    keff_kernel<<<MM * KC, 128, 0, stream>>>(cb, A, keffdT, keff16);
    argmax_mfma<<<1024, 256, 0, stream>>>(latent, keff16, out, wl_cnt, wl);
    rescue_kernel<<<1024, 256, 0, stream>>>(latent, keffdT, wl_cnt, wl, out);
}